// Round 5
// baseline (266.891 us; speedup 1.0000x reference)
//
#include <hip/hip_runtime.h>
#include <hip/hip_bf16.h>
#include <cmath>

#define NB 4
#define NM 32
#define DKc 256
#define DVc 32
#define NP 4096

using bf16x8 = __attribute__((ext_vector_type(8))) short;
using f32x4  = __attribute__((ext_vector_type(4))) float;

__device__ __forceinline__ unsigned short f2bf(float f) {
    union { float f; unsigned u; } x; x.f = f;
    unsigned r = 0x7FFFu + ((x.u >> 16) & 1u);
    return (unsigned short)((x.u + r) >> 16);
}

// ---------------- k_prep: fc transpose (1024 blocks) + W transposes (32) + vproj (64) ----------------
__global__ __launch_bounds__(256) void k_prep(
    const float* __restrict__ fc, unsigned short* __restrict__ fcT,
    const float* __restrict__ Q, unsigned short* __restrict__ WTq,
    const float* __restrict__ K, unsigned short* __restrict__ WTk,
    const float* __restrict__ fm, const float* __restrict__ V, float* __restrict__ vproj) {
    int x = blockIdx.x;
    int t = threadIdx.x;
    if (x < 1056) {
        __shared__ float tile[64][65];
        const float* s; unsigned short* d; int R, C, r0, c0;
        if (x < 1024) {
            int bb = x >> 8, rest = x & 255;
            R = 256; C = 4096;
            r0 = (rest >> 6) * 64; c0 = (rest & 63) * 64;
            s = fc + (long)bb * 256 * 4096; d = fcT + (long)bb * 256 * 4096;
        } else {
            int i = x - 1024;
            int mat = i >> 4, idx = i & 15;
            R = 256; C = 256;
            r0 = (idx >> 2) * 64; c0 = (idx & 3) * 64;
            s = mat ? K : Q; d = mat ? WTk : WTq;
        }
        #pragma unroll
        for (int j = 0; j < 16; ++j) {
            int i = t + 256 * j;
            int r = i >> 6, c = i & 63;
            tile[r][c] = s[(long)(r0 + r) * C + c0 + c];
        }
        __syncthreads();
        #pragma unroll
        for (int j = 0; j < 8; ++j) {
            int i = t + 256 * j;
            int row = i >> 5;
            int pr = i & 31;
            float f0 = tile[2 * pr][row];
            float f1 = tile[2 * pr + 1][row];
            unsigned pack = (unsigned)f2bf(f0) | ((unsigned)f2bf(f1) << 16);
            reinterpret_cast<unsigned*>(d)[(((long)(c0 + row) * R + r0) >> 1) + pr] = pack;
        }
    } else {
        __shared__ float Vl[32][32];
        __shared__ float fml[32][256];
        int i = x - 1056;
        int b = i >> 4, p0 = (i & 15) * 256;
        #pragma unroll
        for (int j = 0; j < 4; ++j) { int ii = t + 256 * j; Vl[ii >> 5][ii & 31] = V[ii]; }
        for (int j = 0; j < 32; ++j) {
            int ii = t + 256 * j;
            int dd = ii >> 8, c = ii & 255;
            fml[dd][c] = fm[((long)b * DVc + dd) * NP + p0 + c];
        }
        __syncthreads();
        float acc[32];
        #pragma unroll
        for (int e = 0; e < 32; ++e) acc[e] = 0.f;
        for (int dd = 0; dd < 32; ++dd) {
            float fv = fml[dd][t];
            #pragma unroll
            for (int e = 0; e < 32; ++e) acc[e] += fv * Vl[dd][e];
        }
        #pragma unroll
        for (int e = 0; e < 32; ++e) vproj[((long)b * DVc + e) * NP + p0 + t] = acc[e];
    }
}

// ---------------- k_proj: full-e (256) per 64-p tile. grid (64, 8=b*mat) ----------------
// both outputs fp32 [b][e][p]: mat==0 -> qproj, mat==1 -> kproj
__global__ __launch_bounds__(256) void k_proj(
    const unsigned short* __restrict__ WTq, const unsigned short* __restrict__ WTk,
    const unsigned short* __restrict__ fcT,
    float* __restrict__ qproj, float* __restrict__ kproj) {
    int t = threadIdx.x;
    int wave = t >> 6, lane = t & 63;
    int y = blockIdx.y;
    int b = y & 3, mat = y >> 2;
    int p0 = blockIdx.x * 64;
    int ln = lane & 15, quad = lane >> 4;
    const unsigned short* WT = mat ? WTk : WTq;
    float* dst = mat ? kproj : qproj;
    int e0w = wave * 64;
    const unsigned short* bbase = fcT + ((long)b * NP + p0 + ln) * DKc + quad * 8;
    f32x4 acc[4][4] = {};
    for (int kk = 0; kk < DKc; kk += 32) {
        bf16x8 a[4], bb[4];
        #pragma unroll
        for (int i = 0; i < 4; ++i)
            a[i] = *reinterpret_cast<const bf16x8*>(WT + (long)(e0w + i * 16 + ln) * DKc + quad * 8 + kk);
        #pragma unroll
        for (int j = 0; j < 4; ++j)
            bb[j] = *reinterpret_cast<const bf16x8*>(bbase + (long)j * 16 * DKc + kk);
        #pragma unroll
        for (int i = 0; i < 4; ++i)
            #pragma unroll
            for (int j = 0; j < 4; ++j)
                acc[i][j] = __builtin_amdgcn_mfma_f32_16x16x32_bf16(a[i], bb[j], acc[i][j], 0, 0, 0);
    }
    #pragma unroll
    for (int i = 0; i < 4; ++i)
        #pragma unroll
        for (int j = 0; j < 4; ++j)
            #pragma unroll
            for (int r = 0; r < 4; ++r) {
                int e = e0w + i * 16 + quad * 4 + r, p = p0 + j * 16 + ln;
                dst[((long)b * DKc + e) * NP + p] = acc[i][j][r];
            }
}

// ---------------- k_scores: e-chunk partial scores ----------------
// grid (wseg=16, ec=8, b=4) = 512 blocks, 256 thr. Thread owns 1 w, acc[32] over its e-chunk.
// linear id = wseg + 16*ec + 128*b -> b-stride/ec-stride multiples of 8 => same XCD (L2 k-reuse x4).
__global__ __launch_bounds__(256, 2) void k_scores(
    const float* __restrict__ qproj, const float* __restrict__ kproj,
    const float* __restrict__ kbuf, float* __restrict__ partial) {
    int t = threadIdx.x;
    int wseg = blockIdx.x, ec = blockIdx.y, b = blockIdx.z;
    int w = wseg * 256 + t;
    int e0 = ec * 32;
    const float* qp = qproj + ((long)b * DKc + e0) * NP + w;
    float acc[NM];
    #pragma unroll
    for (int m = 0; m < NM; ++m) acc[m] = 0.f;
    #pragma unroll 2
    for (int e = 0; e < 32; ++e) {
        float qv = qp[(long)e * NP];
        float kv[NM];
        #pragma unroll
        for (int m = 0; m < NM; ++m) {
            const float* kp = (m < 4 ? kproj + (long)m * DKc * NP
                                     : kbuf + (long)(m - 4) * DKc * NP);
            kv[m] = kp[(long)(e0 + e) * NP + w];
        }
        #pragma unroll
        for (int m = 0; m < NM; ++m) acc[m] += qv * kv[m];
    }
    float* pp = partial + (((long)b * 8 + ec) * NM) * NP + w;
    #pragma unroll
    for (int m = 0; m < NM; ++m) pp[(long)m * NP] = acc[m];
}

// ---------------- k_out: partial-reduce + softmax(w) + ctx + epilogue ----------------
// grid 256 (b*64+hrow), 512 thr.
__global__ __launch_bounds__(512) void k_out(
    const float* __restrict__ partial, const float* __restrict__ vproj,
    const float* __restrict__ vbuf, const float* __restrict__ fm,
    float* __restrict__ out, float scale) {
    __shared__ float sc[32][68];
    int t = threadIdx.x;
    int b = blockIdx.x >> 6, hrow = blockIdx.x & 63;
    int p0h = hrow * 64;
    int wave = t >> 6, lane = t & 63;
    {   // reduce 8 e-chunk partials; mg = t>>6 (8 groups of 4 m), w = t&63
        int w = t & 63, mg = t >> 6;
        float s[4] = {0.f, 0.f, 0.f, 0.f};
        #pragma unroll
        for (int c = 0; c < 8; ++c) {
            const float* pp = partial + (((long)b * 8 + c) * NM + mg * 4) * NP + p0h + w;
            #pragma unroll
            for (int mi = 0; mi < 4; ++mi) s[mi] += pp[(long)mi * NP];
        }
        #pragma unroll
        for (int mi = 0; mi < 4; ++mi) sc[mg * 4 + mi][w] = s[mi] * scale;
    }
    __syncthreads();
    // softmax over w: each wave handles 4 rows
    #pragma unroll
    for (int r = 0; r < 4; ++r) {
        int m = wave * 4 + r;
        float x = sc[m][lane];
        float mx = x;
        #pragma unroll
        for (int d = 1; d < 64; d <<= 1) mx = fmaxf(mx, __shfl_xor(mx, d));
        float e = __expf(x - mx);
        float sum = e;
        #pragma unroll
        for (int d = 1; d < 64; d <<= 1) sum += __shfl_xor(sum, d);
        sc[m][lane] = e / sum;
    }
    __syncthreads();
    {   // ctx + epilogue: dg = t>>6 (8 groups x 4 d), w = t&63
        int dg = t >> 6, w = t & 63;
        float c4[4] = {0.f, 0.f, 0.f, 0.f};
        #pragma unroll
        for (int m = 0; m < NM; ++m) {
            float a = sc[m][w];
            const float* vp = (m < 4 ? vproj + (long)m * DVc * NP : vbuf + (long)(m - 4) * DVc * NP)
                              + (long)(dg * 4) * NP + p0h + w;
            #pragma unroll
            for (int i = 0; i < 4; ++i) c4[i] += a * vp[(long)i * NP];
        }
        #pragma unroll
        for (int i = 0; i < 4; ++i) {
            long gi = ((long)b * DVc + dg * 4 + i) * NP + p0h + w;
            out[gi] = fm[gi] + 0.5f * c4[i];
        }
    }
}

extern "C" void kernel_launch(void* const* d_in, const int* in_sizes, int n_in,
                              void* d_out, int out_size, void* d_ws, size_t ws_size,
                              hipStream_t stream) {
    const float* fc = (const float*)d_in[0];
    const float* fm = (const float*)d_in[1];
    const float* kb = (const float*)d_in[2];
    const float* vb = (const float*)d_in[3];
    const float* Q  = (const float*)d_in[4];
    const float* K  = (const float*)d_in[5];
    const float* V  = (const float*)d_in[6];
    float* out = (float*)d_out;
    char* ws = (char*)d_ws;
    // layout: qproj/kproj/vproj persistent; fcT+WT dead after k_proj, overlaid by partial.
    float*          qproj = (float*)(ws);                          // 16777216 B
    float*          kproj = (float*)(ws + 16777216);               // 16777216 B
    float*          vproj = (float*)(ws + 33554432);               //  2097152 B
    unsigned short* fcT   = (unsigned short*)(ws + 35651584);      //  8388608 B
    unsigned short* WTq   = (unsigned short*)(ws + 44040192);      //   131072 B
    unsigned short* WTk   = (unsigned short*)(ws + 44171264);      //   131072 B
    float*          partial = (float*)(ws + 35651584);             // 16777216 B (overlay)
    float scale = (float)(log(135168.0) / log(1000.0) / 16.0);

    hipLaunchKernelGGL(k_prep, dim3(1120), dim3(256), 0, stream,
                       fc, fcT, Q, WTq, K, WTk, fm, V, vproj);
    hipLaunchKernelGGL(k_proj, dim3(64, 8), dim3(256), 0, stream,
                       WTq, WTk, fcT, qproj, kproj);
    hipLaunchKernelGGL(k_scores, dim3(16, 8, 4), dim3(256), 0, stream,
                       qproj, kproj, kb, partial);
    hipLaunchKernelGGL(k_out, dim3(256), dim3(512), 0, stream,
                       partial, vproj, vb, fm, out, scale);
}

// Round 6
// 244.821 us; speedup vs baseline: 1.0902x; 1.0902x over previous
//
#include <hip/hip_runtime.h>
#include <hip/hip_bf16.h>
#include <cmath>

#define NB 4
#define NM 32
#define DKc 256
#define DVc 32
#define NP 4096

using bf16x8 = __attribute__((ext_vector_type(8))) short;
using f32x4  = __attribute__((ext_vector_type(4))) float;
using f32x2  = __attribute__((ext_vector_type(2))) float;

__device__ __forceinline__ unsigned short f2bf(float f) {
    union { float f; unsigned u; } x; x.f = f;
    unsigned r = 0x7FFFu + ((x.u >> 16) & 1u);
    return (unsigned short)((x.u + r) >> 16);
}

// ---------------- k_prep: fc transpose (1024 blocks) + W transposes (32) + vproj (64) ----------------
__global__ __launch_bounds__(256) void k_prep(
    const float* __restrict__ fc, unsigned short* __restrict__ fcT,
    const float* __restrict__ Q, unsigned short* __restrict__ WTq,
    const float* __restrict__ K, unsigned short* __restrict__ WTk,
    const float* __restrict__ fm, const float* __restrict__ V, float* __restrict__ vproj) {
    int x = blockIdx.x;
    int t = threadIdx.x;
    if (x < 1056) {
        __shared__ float tile[64][65];
        const float* s; unsigned short* d; int R, C, r0, c0;
        if (x < 1024) {
            int bb = x >> 8, rest = x & 255;
            R = 256; C = 4096;
            r0 = (rest >> 6) * 64; c0 = (rest & 63) * 64;
            s = fc + (long)bb * 256 * 4096; d = fcT + (long)bb * 256 * 4096;
        } else {
            int i = x - 1024;
            int mat = i >> 4, idx = i & 15;
            R = 256; C = 256;
            r0 = (idx >> 2) * 64; c0 = (idx & 3) * 64;
            s = mat ? K : Q; d = mat ? WTk : WTq;
        }
        #pragma unroll
        for (int j = 0; j < 16; ++j) {
            int i = t + 256 * j;
            int r = i >> 6, c = i & 63;
            tile[r][c] = s[(long)(r0 + r) * C + c0 + c];
        }
        __syncthreads();
        #pragma unroll
        for (int j = 0; j < 8; ++j) {
            int i = t + 256 * j;
            int row = i >> 5;
            int pr = i & 31;
            float f0 = tile[2 * pr][row];
            float f1 = tile[2 * pr + 1][row];
            unsigned pack = (unsigned)f2bf(f0) | ((unsigned)f2bf(f1) << 16);
            reinterpret_cast<unsigned*>(d)[(((long)(c0 + row) * R + r0) >> 1) + pr] = pack;
        }
    } else {
        __shared__ float Vl[32][32];
        __shared__ float fml[32][256];
        int i = x - 1056;
        int b = i >> 4, p0 = (i & 15) * 256;
        #pragma unroll
        for (int j = 0; j < 4; ++j) { int ii = t + 256 * j; Vl[ii >> 5][ii & 31] = V[ii]; }
        for (int j = 0; j < 32; ++j) {
            int ii = t + 256 * j;
            int dd = ii >> 8, c = ii & 255;
            fml[dd][c] = fm[((long)b * DVc + dd) * NP + p0 + c];
        }
        __syncthreads();
        float acc[32];
        #pragma unroll
        for (int e = 0; e < 32; ++e) acc[e] = 0.f;
        for (int dd = 0; dd < 32; ++dd) {
            float fv = fml[dd][t];
            #pragma unroll
            for (int e = 0; e < 32; ++e) acc[e] += fv * Vl[dd][e];
        }
        #pragma unroll
        for (int e = 0; e < 32; ++e) vproj[((long)b * DVc + e) * NP + p0 + t] = acc[e];
    }
}

// ---------------- k_proj: full-e (256) per 64-p tile. grid (64, 8=b*mat) ----------------
// both outputs fp32 [b][e][p]: mat==0 -> qproj, mat==1 -> kproj
__global__ __launch_bounds__(256) void k_proj(
    const unsigned short* __restrict__ WTq, const unsigned short* __restrict__ WTk,
    const unsigned short* __restrict__ fcT,
    float* __restrict__ qproj, float* __restrict__ kproj) {
    int t = threadIdx.x;
    int wave = t >> 6, lane = t & 63;
    int y = blockIdx.y;
    int b = y & 3, mat = y >> 2;
    int p0 = blockIdx.x * 64;
    int ln = lane & 15, quad = lane >> 4;
    const unsigned short* WT = mat ? WTk : WTq;
    float* dst = mat ? kproj : qproj;
    int e0w = wave * 64;
    const unsigned short* bbase = fcT + ((long)b * NP + p0 + ln) * DKc + quad * 8;
    f32x4 acc[4][4] = {};
    for (int kk = 0; kk < DKc; kk += 32) {
        bf16x8 a[4], bb[4];
        #pragma unroll
        for (int i = 0; i < 4; ++i)
            a[i] = *reinterpret_cast<const bf16x8*>(WT + (long)(e0w + i * 16 + ln) * DKc + quad * 8 + kk);
        #pragma unroll
        for (int j = 0; j < 4; ++j)
            bb[j] = *reinterpret_cast<const bf16x8*>(bbase + (long)j * 16 * DKc + kk);
        #pragma unroll
        for (int i = 0; i < 4; ++i)
            #pragma unroll
            for (int j = 0; j < 4; ++j)
                acc[i][j] = __builtin_amdgcn_mfma_f32_16x16x32_bf16(a[i], bb[j], acc[i][j], 0, 0, 0);
    }
    #pragma unroll
    for (int i = 0; i < 4; ++i)
        #pragma unroll
        for (int j = 0; j < 4; ++j)
            #pragma unroll
            for (int r = 0; r < 4; ++r) {
                int e = e0w + i * 16 + quad * 4 + r, p = p0 + j * 16 + ln;
                dst[((long)b * DKc + e) * NP + p] = acc[i][j][r];
            }
}

// ---------------- k_scores: all-b, m-quad, e-chunk partial scores ----------------
// grid (wseg=8, ec=8, mq=8) = 512 blocks, 256 thr. Thread owns a w-pair (float2).
// linear id = wseg + 8*ec + 64*mq: mq-sharers (same q-tile) are 64 apart => same XCD.
// k is read by exactly ONE block (no amplification); q re-read x8 but L2-resident.
__global__ __launch_bounds__(256, 2) void k_scores(
    const float* __restrict__ qproj, const float* __restrict__ kproj,
    const float* __restrict__ kbuf, float* __restrict__ partial) {
    int t = threadIdx.x;
    int wseg = blockIdx.x, ec = blockIdx.y, mq = blockIdx.z;
    int w0 = wseg * 512 + t * 2;
    int e0 = ec * 32;
    const float* kp[4];
    #pragma unroll
    for (int mi = 0; mi < 4; ++mi) {
        int m = mq * 4 + mi;
        kp[mi] = (m < 4 ? kproj + (long)m * DKc * NP : kbuf + (long)(m - 4) * DKc * NP)
                 + (long)e0 * NP + w0;
    }
    const float* qp[4];
    #pragma unroll
    for (int b = 0; b < 4; ++b)
        qp[b] = qproj + ((long)b * DKc + e0) * NP + w0;

    f32x2 acc[4][4];
    #pragma unroll
    for (int b = 0; b < 4; ++b)
        #pragma unroll
        for (int mi = 0; mi < 4; ++mi) acc[b][mi] = (f32x2){0.f, 0.f};

    // e-loop unrolled by 4: 32 independent float2 loads batched, then 128 FMAs
    for (int e4 = 0; e4 < 32; e4 += 4) {
        f32x2 qv[4][4], kv[4][4];
        #pragma unroll
        for (int u = 0; u < 4; ++u) {
            long off = (long)(e4 + u) * NP;
            #pragma unroll
            for (int b = 0; b < 4; ++b)
                qv[u][b] = *reinterpret_cast<const f32x2*>(qp[b] + off);
            #pragma unroll
            for (int mi = 0; mi < 4; ++mi)
                kv[u][mi] = *reinterpret_cast<const f32x2*>(kp[mi] + off);
        }
        #pragma unroll
        for (int u = 0; u < 4; ++u)
            #pragma unroll
            for (int b = 0; b < 4; ++b)
                #pragma unroll
                for (int mi = 0; mi < 4; ++mi)
                    acc[b][mi] += qv[u][b] * kv[u][mi];
    }
    #pragma unroll
    for (int b = 0; b < 4; ++b)
        #pragma unroll
        for (int mi = 0; mi < 4; ++mi) {
            float* pp = partial + (((long)b * 8 + ec) * NM + mq * 4 + mi) * NP + w0;
            *reinterpret_cast<f32x2*>(pp) = acc[b][mi];
        }
}

// ---------------- k_out: partial-reduce + softmax(w) + ctx + epilogue ----------------
// grid 256 (b*64+hrow), 512 thr.
__global__ __launch_bounds__(512) void k_out(
    const float* __restrict__ partial, const float* __restrict__ vproj,
    const float* __restrict__ vbuf, const float* __restrict__ fm,
    float* __restrict__ out, float scale) {
    __shared__ float sc[32][68];
    int t = threadIdx.x;
    int b = blockIdx.x >> 6, hrow = blockIdx.x & 63;
    int p0h = hrow * 64;
    int wave = t >> 6, lane = t & 63;
    {   // reduce 8 e-chunk partials; mg = t>>6 (8 groups of 4 m), w = t&63
        int w = t & 63, mg = t >> 6;
        float s[4] = {0.f, 0.f, 0.f, 0.f};
        #pragma unroll
        for (int c = 0; c < 8; ++c) {
            const float* pp = partial + (((long)b * 8 + c) * NM + mg * 4) * NP + p0h + w;
            #pragma unroll
            for (int mi = 0; mi < 4; ++mi) s[mi] += pp[(long)mi * NP];
        }
        #pragma unroll
        for (int mi = 0; mi < 4; ++mi) sc[mg * 4 + mi][w] = s[mi] * scale;
    }
    __syncthreads();
    // softmax over w: each wave handles 4 rows
    #pragma unroll
    for (int r = 0; r < 4; ++r) {
        int m = wave * 4 + r;
        float x = sc[m][lane];
        float mx = x;
        #pragma unroll
        for (int d = 1; d < 64; d <<= 1) mx = fmaxf(mx, __shfl_xor(mx, d));
        float e = __expf(x - mx);
        float sum = e;
        #pragma unroll
        for (int d = 1; d < 64; d <<= 1) sum += __shfl_xor(sum, d);
        sc[m][lane] = e / sum;
    }
    __syncthreads();
    {   // ctx + epilogue: dg = t>>6 (8 groups x 4 d), w = t&63
        int dg = t >> 6, w = t & 63;
        float c4[4] = {0.f, 0.f, 0.f, 0.f};
        #pragma unroll
        for (int m = 0; m < NM; ++m) {
            float a = sc[m][w];
            const float* vp = (m < 4 ? vproj + (long)m * DVc * NP : vbuf + (long)(m - 4) * DVc * NP)
                              + (long)(dg * 4) * NP + p0h + w;
            #pragma unroll
            for (int i = 0; i < 4; ++i) c4[i] += a * vp[(long)i * NP];
        }
        #pragma unroll
        for (int i = 0; i < 4; ++i) {
            long gi = ((long)b * DVc + dg * 4 + i) * NP + p0h + w;
            out[gi] = fm[gi] + 0.5f * c4[i];
        }
    }
}

extern "C" void kernel_launch(void* const* d_in, const int* in_sizes, int n_in,
                              void* d_out, int out_size, void* d_ws, size_t ws_size,
                              hipStream_t stream) {
    const float* fc = (const float*)d_in[0];
    const float* fm = (const float*)d_in[1];
    const float* kb = (const float*)d_in[2];
    const float* vb = (const float*)d_in[3];
    const float* Q  = (const float*)d_in[4];
    const float* K  = (const float*)d_in[5];
    const float* V  = (const float*)d_in[6];
    float* out = (float*)d_out;
    char* ws = (char*)d_ws;
    // layout: qproj/kproj/vproj persistent; fcT+WT dead after k_proj, overlaid by partial.
    float*          qproj = (float*)(ws);                          // 16777216 B
    float*          kproj = (float*)(ws + 16777216);               // 16777216 B
    float*          vproj = (float*)(ws + 33554432);               //  2097152 B
    unsigned short* fcT   = (unsigned short*)(ws + 35651584);      //  8388608 B
    unsigned short* WTq   = (unsigned short*)(ws + 44040192);      //   131072 B
    unsigned short* WTk   = (unsigned short*)(ws + 44171264);      //   131072 B
    float*          partial = (float*)(ws + 35651584);             // 16777216 B (overlay)
    float scale = (float)(log(135168.0) / log(1000.0) / 16.0);

    hipLaunchKernelGGL(k_prep, dim3(1120), dim3(256), 0, stream,
                       fc, fcT, Q, WTq, K, WTk, fm, V, vproj);
    hipLaunchKernelGGL(k_proj, dim3(64, 8), dim3(256), 0, stream,
                       WTq, WTk, fcT, qproj, kproj);
    hipLaunchKernelGGL(k_scores, dim3(8, 8, 8), dim3(256), 0, stream,
                       qproj, kproj, kb, partial);
    hipLaunchKernelGGL(k_out, dim3(256), dim3(512), 0, stream,
                       partial, vproj, vb, fm, out, scale);
}